// Round 12
// baseline (182.250 us; speedup 1.0000x reference)
//
#include <hip/hip_runtime.h>

// YOLO loss on MI355X. Inputs: yhat (N,52,52,255) f32, y (N,52,52,255) f32,
// anchors (3,3,2) f32, epoch (ignored: epoch=1 >= EPOCH_PRIOR=0 -> prior=0).
// Outputs: concat [coord(N), class(N), noobj(N), obj(N), prior(1)] f32.
//
// R11: one cell per LANE. All prior rounds kept 1 cell per 16-lane group ->
// 169 wave-iterations/CU x ~1100cy dependent chain = 78us (matches R3-R10's
// invariant). This kernel: 1-wave blocks stage 24 cells (49.5KB LDS, float4
// coalesced, 3 blocks/CU), phase A computes box/IoU/argmax/coord/obj/noobj
// with lane=cell (16x less redundancy; LDS stride 255 = -1 mod 32 banks ->
// 2-way, free), phase B does class loss in 16-lane-group layout from the
// same slab using sel/ho passed via LDS scratch.

constexpr int SD     = 52;
constexpr int S2     = SD * SD;              // 2704
constexpr int CH     = 255;                  // (5+80)*3
constexpr int CELLS  = 24;                   // cells per block
constexpr int BPI    = (S2 + CELLS - 1) / CELLS;   // 113 (last block: 16 cells)
constexpr float EPSF = 1e-6f;

__device__ __forceinline__ float flog(float x) {
    return __builtin_amdgcn_logf(x) * 0.69314718055994531f;  // v_log_f32 * ln2
}
__device__ __forceinline__ float frcp(float x) {
    return __builtin_amdgcn_rcpf(x);
}
__device__ __forceinline__ float sel3(int s, float a, float b, float c) {
    return (s == 0) ? a : ((s == 1) ? b : c);
}

__global__ __launch_bounds__(64, 4) void yolo_loss_kernel(
    const float* __restrict__ yhat, const float* __restrict__ yt,
    const float* __restrict__ anchors, float* __restrict__ out, int N)
{
    __shared__ __align__(16) float shA[CELLS * CH];   // 24*255*4 = 24480 B
    __shared__ __align__(16) float shT[CELLS * CH];
    __shared__ float ssel[CELLS][3];
    __shared__ float sho [CELLS][3];

    const int lane = threadIdx.x;           // one wave per block
    const int grp  = lane >> 4;
    const int sub  = lane & 15;

    const int n    = blockIdx.x / BPI;
    const int blk  = blockIdx.x - n * BPI;
    const int cell0      = blk * CELLS;
    const int cells_this = min(CELLS, S2 - cell0);
    const int f4n        = cells_this * CH / 4;    // 1530 or 1020 (both exact)

    // ---- stage: pure float4, fully coalesced ----
    const size_t imgBase = (size_t)n * S2 * CH;
    // cell0*CH = blk*6120 (mult of 4); imgBase mult of 4 -> float4-exact
    const float4* __restrict__ gA4 = (const float4*)(yhat + imgBase + (size_t)cell0 * CH);
    const float4* __restrict__ gT4 = (const float4*)(yt   + imgBase + (size_t)cell0 * CH);
    float4* sA4 = (float4*)shA;
    float4* sT4 = (float4*)shT;
    for (int i = lane; i < f4n; i += 64) {
        sA4[i] = gA4[i];
        sT4[i] = gT4[i];
    }
    __syncthreads();

    // anchors[scale_idx=2][b][wh] -> flat offset 12 + 2b
    const float rw0 = frcp(anchors[12]), rh0 = frcp(anchors[13]);
    const float rw1 = frcp(anchors[14]), rh1 = frcp(anchors[15]);
    const float rw2 = frcp(anchors[16]), rh2 = frcp(anchors[17]);
    const float invS = 1.0f / (float)SD;

    float acc_coord = 0.f, acc_class = 0.f, acc_noobj = 0.f, acc_obj = 0.f;

    // ---- phase A: lane = cell; box/IoU/argmax/coord/obj/noobj per-lane ----
    if (lane < cells_this) {
        const float* A = shA + lane * CH;   // stride 255 across lanes: 2-way banks
        const float* T = shT + lane * CH;
        const int cellImg = cell0 + lane;
        const int irow = cellImg / SD;
        const int jcol = cellImg - irow * SD;
        const float jf = (float)jcol, if_ = (float)irow;

        float av[3][5], tv[3][5];
#pragma unroll
        for (int b = 0; b < 3; b++)
#pragma unroll
            for (int k = 0; k < 5; k++) {
                av[b][k] = A[b * 85 + k];
                tv[b][k] = T[b * 85 + k];
            }

        float hx1[3], hx2[3], hy1[3], hy2[3], ha[3];
        float tx1[3], tx2[3], ty1[3], ty2[3], ta[3];
#pragma unroll
        for (int b = 0; b < 3; b++) {
            float w = av[b][2], h = av[b][3];
            float cx = (av[b][0] + jf) * invS, cy = (av[b][1] + if_) * invS;
            hx1[b] = cx - 0.5f * w; hx2[b] = cx + 0.5f * w;
            hy1[b] = cy - 0.5f * h; hy2[b] = cy + 0.5f * h;
            ha[b]  = (hx2[b] - hx1[b]) * (hy2[b] - hy1[b]);
        }
#pragma unroll
        for (int b = 0; b < 3; b++) {
            float w = tv[b][2], h = tv[b][3];
            float cx = (tv[b][0] + jf) * invS, cy = (tv[b][1] + if_) * invS;
            tx1[b] = cx - 0.5f * w; tx2[b] = cx + 0.5f * w;
            ty1[b] = cy - 0.5f * h; ty2[b] = cy + 0.5f * h;
            ta[b]  = (tx2[b] - tx1[b]) * (ty2[b] - ty1[b]);
        }

        float iou[3][3];
#pragma unroll
        for (int bp = 0; bp < 3; bp++)
#pragma unroll
            for (int bt = 0; bt < 3; bt++) {
                float wi = fminf(hx2[bp], tx2[bt]) - fmaxf(hx1[bp], tx1[bt]);
                wi = fmaxf(wi, 0.0f);
                float hi = fminf(hy2[bp], ty2[bt]) - fmaxf(hy1[bp], ty1[bt]);
                hi = fmaxf(hi, 0.0f);
                float inter = wi * hi;
                float uni   = ha[bp] + ta[bt] - inter;
                iou[bp][bt] = inter * frcp(uni + EPSF);
            }

        // no-obj (target 0, NO_OBJ_V3)
#pragma unroll
        for (int bp = 0; bp < 3; bp++) {
            float m = fmaxf(fmaxf(iou[bp][0], iou[bp][1]), iou[bp][2]);
            acc_noobj += (m < 0.7f) ? av[bp][4] * av[bp][4] : 0.0f;
        }

        // argmax (first-max ties, like jnp.argmax) + coord/obj
#pragma unroll
        for (int bt = 0; bt < 3; bt++) {
            int s = 0; float v = iou[0][bt];
            if (iou[1][bt] > v) { v = iou[1][bt]; s = 1; }
            if (iou[2][bt] > v) { s = 2; }

            float hoo = (tv[bt][4] > 0.0f) ? 1.0f : 0.0f;
            float phx = sel3(s, av[0][0], av[1][0], av[2][0]);
            float phy = sel3(s, av[0][1], av[1][1], av[2][1]);
            float phw = sel3(s, av[0][2], av[1][2], av[2][2]);
            float phh = sel3(s, av[0][3], av[1][3], av[2][3]);
            float phc = sel3(s, av[0][4], av[1][4], av[2][4]);
            float rwp = sel3(s, rw0, rw1, rw2);
            float rhp = sel3(s, rh0, rh1, rh2);
            float rwt = (bt == 0) ? rw0 : ((bt == 1) ? rw1 : rw2);
            float rht = (bt == 0) ? rh0 : ((bt == 1) ? rh1 : rh2);
            float dx  = phx - tv[bt][0];
            float dy  = phy - tv[bt][1];
            float dlw = flog(phw * rwp + EPSF) - flog(tv[bt][2] * rwt + EPSF);
            float dlh = flog(phh * rhp + EPSF) - flog(tv[bt][3] * rht + EPSF);
            float csum = dx * dx + dy * dy + dlw * dlw + dlh * dlh;
            acc_coord += csum * hoo * (2.0f - tv[bt][2] * tv[bt][3]);
            float dcf = phc - tv[bt][4];
            acc_obj += dcf * dcf * hoo;

            ssel[lane][bt] = (float)s;
            sho [lane][bt] = hoo;
        }
    }
    __syncthreads();

    // ---- phase B: class loss, 16-lane groups, 4 cells per pass ----
#pragma unroll
    for (int p = 0; p < CELLS / 4; p++) {
        int cell = p * 4 + grp;
        if (cell < cells_this) {
            const float* Ac = shA + cell * CH;
            const float* Tc = shT + cell * CH;
#pragma unroll
            for (int bt = 0; bt < 3; bt++) {
                int sp    = (int)ssel[cell][bt];
                float hob = sho[cell][bt];
                const float* pa = Ac + sp * 85 + 5;
                const float* pt = Tc + bt * 85 + 5;
                float s = 0.0f;
#pragma unroll
                for (int k = 0; k < 5; k++) {
                    float d = pa[sub + 16 * k] - pt[sub + 16 * k];
                    s += d * d;
                }
                acc_class += s * hob;
            }
        }
    }

    // ---- wave reduction (no replication anywhere now) ----
#pragma unroll
    for (int off = 1; off < 64; off <<= 1) {
        acc_coord += __shfl_xor(acc_coord, off, 64);
        acc_class += __shfl_xor(acc_class, off, 64);
        acc_noobj += __shfl_xor(acc_noobj, off, 64);
        acc_obj   += __shfl_xor(acc_obj,   off, 64);
    }
    if (lane < 4) {
        float v = (lane == 0) ? acc_coord :
                  (lane == 1) ? acc_class :
                  (lane == 2) ? acc_noobj : acc_obj;
        atomicAdd(&out[lane * N + n], v);
    }
}

extern "C" void kernel_launch(void* const* d_in, const int* in_sizes, int n_in,
                              void* d_out, int out_size, void* d_ws, size_t ws_size,
                              hipStream_t stream) {
    const float* yhat = (const float*)d_in[0];
    const float* yv   = (const float*)d_in[1];
    const float* anc  = (const float*)d_in[2];
    float* out = (float*)d_out;

    const int N = in_sizes[0] / (S2 * CH);

    hipMemsetAsync(d_out, 0, (size_t)out_size * sizeof(float), stream);

    dim3 grid(N * BPI);
    yolo_loss_kernel<<<grid, 64, 0, stream>>>(yhat, yv, anc, out, N);
}